// Round 1
// baseline (194.458 us; speedup 1.0000x reference)
//
#include <hip/hip_runtime.h>
#include <math.h>

#define NQ 4
#define NL 2
#define DIM 16          // 2^NQ
#define BATCH 16
#define CH 256
#define HW 16384        // 128*128

// ---------------- Kernel 1: per-(b,c) mean over H*W ----------------
__global__ void pool_kernel(const float* __restrict__ x, float* __restrict__ pooled) {
    const int bc = blockIdx.x;                       // 0..4095
    const float4* x4 = (const float4*)(x + (size_t)bc * HW);
    const int tid = threadIdx.x;                     // 256 threads
    float s = 0.f;
#pragma unroll
    for (int k = 0; k < 16; ++k) {                   // 16 float4 / thread = 16384 elems/block
        float4 v = x4[tid + k * 256];
        s += v.x + v.y + v.z + v.w;
    }
    // wave (64-lane) shuffle reduce
#pragma unroll
    for (int off = 32; off > 0; off >>= 1) s += __shfl_down(s, off, 64);
    __shared__ float partial[4];
    if ((tid & 63) == 0) partial[tid >> 6] = s;
    __syncthreads();
    if (tid == 0)
        pooled[bc] = (partial[0] + partial[1] + partial[2] + partial[3]) * (1.0f / HW);
}

// ---------------- Kernel 2: encoder + 4-qubit circuit + gates ----------------
// one block, 256 threads. Writes gates1p[b*CH+c] = 1 + sigmoid(...)
__global__ void gate_kernel(const float* __restrict__ pooled,
                            const float* __restrict__ enc_w,  // [NQ, CH]
                            const float* __restrict__ enc_b,  // [NQ]
                            const float* __restrict__ qw,     // [NL, NQ, 3]
                            const float* __restrict__ proj_w, // [CH, NQ]
                            const float* __restrict__ proj_b, // [CH]
                            float* __restrict__ gates1p) {
    __shared__ float sp[BATCH * CH];
    __shared__ float sz[BATCH][NQ];
    __shared__ float sref[BATCH][NQ];
    const int tid = threadIdx.x;

    for (int i = tid; i < BATCH * CH; i += 256) sp[i] = pooled[i];
    __syncthreads();

    // z = tanh(pooled @ enc_w^T + enc_b) : 64 (b,q) dots over 256
    if (tid < BATCH * NQ) {
        const int b = tid >> 2, q = tid & 3;
        float acc = enc_b[q];
        for (int c = 0; c < CH; ++c) acc += sp[b * CH + c] * enc_w[q * CH + c];
        sz[b][q] = tanhf(acc);
    }
    __syncthreads();

    // statevector simulation: one thread per batch
    if (tid < BATCH) {
        const int b = tid;
        float re[DIM], im[DIM];
#pragma unroll
        for (int i = 0; i < DIM; ++i) { re[i] = 0.f; im[i] = 0.f; }
        re[0] = 1.f;

        // AngleEmbedding: RY(z_w) on wire w (wire 0 = MSB of state index)
        for (int w = 0; w < NQ; ++w) {
            const float a = sz[b][w] * 0.5f;
            const float cc = cosf(a), ss = sinf(a);
            const int m = 1 << (3 - w);
#pragma unroll
            for (int i = 0; i < DIM; ++i) {
                if (i & m) continue;
                const int j = i | m;
                const float r0 = cc * re[i] - ss * re[j];
                const float i0 = cc * im[i] - ss * im[j];
                const float r1 = ss * re[i] + cc * re[j];
                const float i1 = ss * im[i] + cc * im[j];
                re[i] = r0; im[i] = i0; re[j] = r1; im[j] = i1;
            }
        }

        // StronglyEntanglingLayers
        for (int l = 0; l < NL; ++l) {
            for (int w = 0; w < NQ; ++w) {
                const float phi = qw[(l * NQ + w) * 3 + 0];
                const float th  = qw[(l * NQ + w) * 3 + 1];
                const float om  = qw[(l * NQ + w) * 3 + 2];
                const float ct = cosf(0.5f * th), st = sinf(0.5f * th);
                const float am = -0.5f * (phi + om);   // e_m = exp(i*am)
                const float ad =  0.5f * (phi - om);   // e_d = exp(i*ad)
                const float emr = cosf(am), emi = sinf(am);
                const float edr = cosf(ad), edi = sinf(ad);
                // U = [[e_m*ct, -e_d*st], [conj(e_d)*st, conj(e_m)*ct]]
                const float u00r =  emr * ct, u00i =  emi * ct;
                const float u01r = -edr * st, u01i = -edi * st;
                const float u10r =  edr * st, u10i = -edi * st;
                const float u11r =  emr * ct, u11i = -emi * ct;
                const int m = 1 << (3 - w);
#pragma unroll
                for (int i = 0; i < DIM; ++i) {
                    if (i & m) continue;
                    const int j = i | m;
                    const float ar = re[i], ai = im[i], br = re[j], bi = im[j];
                    re[i] = u00r * ar - u00i * ai + u01r * br - u01i * bi;
                    im[i] = u00r * ai + u00i * ar + u01r * bi + u01i * br;
                    re[j] = u10r * ar - u10i * ai + u11r * br - u11i * bi;
                    im[j] = u10r * ai + u10i * ar + u11r * bi + u11i * br;
                }
            }
            const int r = (l % (NQ - 1)) + 1;
            for (int w = 0; w < NQ; ++w) {
                const int t = (w + r) % NQ;
                const int cm = 1 << (3 - w);
                const int tm = 1 << (3 - t);
#pragma unroll
                for (int i = 0; i < DIM; ++i) {
                    if ((i & cm) && !(i & tm)) {
                        const int j = i | tm;
                        float tr = re[i]; re[i] = re[j]; re[j] = tr;
                        float ti = im[i]; im[i] = im[j]; im[j] = ti;
                    }
                }
            }
        }

        // PauliZ expvals
        float p[DIM];
#pragma unroll
        for (int i = 0; i < DIM; ++i) p[i] = re[i] * re[i] + im[i] * im[i];
        for (int w = 0; w < NQ; ++w) {
            const int m = 1 << (3 - w);
            float ev = 0.f;
#pragma unroll
            for (int i = 0; i < DIM; ++i) ev += (i & m) ? -p[i] : p[i];
            sref[b][w] = ev;
        }
    }
    __syncthreads();

    // gates1p[b,c] = 1 + sigmoid(refined @ proj_w^T + proj_b)
    const int c = tid;
    const float pw0 = proj_w[c * NQ + 0], pw1 = proj_w[c * NQ + 1];
    const float pw2 = proj_w[c * NQ + 2], pw3 = proj_w[c * NQ + 3];
    const float pb = proj_b[c];
    for (int b = 0; b < BATCH; ++b) {
        const float acc = sref[b][0] * pw0 + sref[b][1] * pw1 +
                          sref[b][2] * pw2 + sref[b][3] * pw3 + pb;
        gates1p[b * CH + c] = 1.f + 1.f / (1.f + expf(-acc));
    }
}

// ---------------- Kernel 3: out = x * gates1p[b,c] ----------------
__global__ void scale_kernel(const float* __restrict__ x,
                             const float* __restrict__ gates1p,
                             float* __restrict__ out) {
    const float4* x4 = (const float4*)x;
    float4* o4 = (float4*)out;
    const int n4 = BATCH * CH * HW / 4;   // 16,777,216
    for (int idx = blockIdx.x * blockDim.x + threadIdx.x; idx < n4;
         idx += gridDim.x * blockDim.x) {
        const int bc = idx >> 12;         // (idx*4) / 16384
        const float g = gates1p[bc];
        float4 v = x4[idx];
        v.x *= g; v.y *= g; v.z *= g; v.w *= g;
        o4[idx] = v;
    }
}

extern "C" void kernel_launch(void* const* d_in, const int* in_sizes, int n_in,
                              void* d_out, int out_size, void* d_ws, size_t ws_size,
                              hipStream_t stream) {
    const float* x      = (const float*)d_in[0];
    const float* enc_w  = (const float*)d_in[1];
    const float* enc_b  = (const float*)d_in[2];
    const float* qw     = (const float*)d_in[3];
    const float* proj_w = (const float*)d_in[4];
    const float* proj_b = (const float*)d_in[5];
    float* out = (float*)d_out;

    float* pooled  = (float*)d_ws;            // [16*256]
    float* gates1p = pooled + BATCH * CH;     // [16*256]

    pool_kernel<<<BATCH * CH, 256, 0, stream>>>(x, pooled);
    gate_kernel<<<1, 256, 0, stream>>>(pooled, enc_w, enc_b, qw, proj_w, proj_b, gates1p);
    scale_kernel<<<2048, 256, 0, stream>>>(x, gates1p, out);
}

// Round 3
// 154.106 us; speedup vs baseline: 1.2619x; 1.2619x over previous
//
#include <hip/hip_runtime.h>
#include <math.h>

#define NQ 4
#define NL 2
#define DIM 16          // 2^NQ
#define BATCH 16
#define CH 256
#define HW 16384        // 128*128

typedef float floatx4 __attribute__((ext_vector_type(4)));

// ---------------- Kernel 1: per-(b,c) mean over H*W ----------------
__global__ void pool_kernel(const float* __restrict__ x, float* __restrict__ pooled) {
    const int bc = blockIdx.x;                       // 0..4095
    const floatx4* x4 = (const floatx4*)(x + (size_t)bc * HW);
    const int tid = threadIdx.x;                     // 256 threads
    float s = 0.f;
#pragma unroll
    for (int k = 0; k < 16; ++k) {                   // 16 float4 / thread = 16384 elems/block
        floatx4 v = x4[tid + k * 256];
        s += v.x + v.y + v.z + v.w;
    }
    // wave (64-lane) shuffle reduce
#pragma unroll
    for (int off = 32; off > 0; off >>= 1) s += __shfl_down(s, off, 64);
    __shared__ float partial[4];
    if ((tid & 63) == 0) partial[tid >> 6] = s;
    __syncthreads();
    if (tid == 0)
        pooled[bc] = (partial[0] + partial[1] + partial[2] + partial[3]) * (1.0f / HW);
}

// ---------------- Kernel 2: encoder + 4-qubit circuit + gates ----------------
// one block, 256 threads. Writes gates1p[b*CH+c] = 1 + sigmoid(...)
__global__ void gate_kernel(const float* __restrict__ pooled,
                            const float* __restrict__ enc_w,  // [NQ, CH]
                            const float* __restrict__ enc_b,  // [NQ]
                            const float* __restrict__ qw,     // [NL, NQ, 3]
                            const float* __restrict__ proj_w, // [CH, NQ]
                            const float* __restrict__ proj_b, // [CH]
                            float* __restrict__ gates1p) {
    __shared__ float sp[BATCH * CH];
    __shared__ float sz[BATCH][NQ];
    __shared__ float sref[BATCH][NQ];
    const int tid = threadIdx.x;

    for (int i = tid; i < BATCH * CH; i += 256) sp[i] = pooled[i];
    __syncthreads();

    // z = tanh(pooled @ enc_w^T + enc_b) : 64 (b,q) dots over 256
    if (tid < BATCH * NQ) {
        const int b = tid >> 2, q = tid & 3;
        float acc = enc_b[q];
        for (int c = 0; c < CH; ++c) acc += sp[b * CH + c] * enc_w[q * CH + c];
        sz[b][q] = tanhf(acc);
    }
    __syncthreads();

    // statevector simulation: one thread per batch
    if (tid < BATCH) {
        const int b = tid;
        float re[DIM], im[DIM];
#pragma unroll
        for (int i = 0; i < DIM; ++i) { re[i] = 0.f; im[i] = 0.f; }
        re[0] = 1.f;

        // AngleEmbedding: RY(z_w) on wire w (wire 0 = MSB of state index)
        for (int w = 0; w < NQ; ++w) {
            const float a = sz[b][w] * 0.5f;
            const float cc = cosf(a), ss = sinf(a);
            const int m = 1 << (3 - w);
#pragma unroll
            for (int i = 0; i < DIM; ++i) {
                if (i & m) continue;
                const int j = i | m;
                const float r0 = cc * re[i] - ss * re[j];
                const float i0 = cc * im[i] - ss * im[j];
                const float r1 = ss * re[i] + cc * re[j];
                const float i1 = ss * im[i] + cc * im[j];
                re[i] = r0; im[i] = i0; re[j] = r1; im[j] = i1;
            }
        }

        // StronglyEntanglingLayers
        for (int l = 0; l < NL; ++l) {
            for (int w = 0; w < NQ; ++w) {
                const float phi = qw[(l * NQ + w) * 3 + 0];
                const float th  = qw[(l * NQ + w) * 3 + 1];
                const float om  = qw[(l * NQ + w) * 3 + 2];
                const float ct = cosf(0.5f * th), st = sinf(0.5f * th);
                const float am = -0.5f * (phi + om);   // e_m = exp(i*am)
                const float ad =  0.5f * (phi - om);   // e_d = exp(i*ad)
                const float emr = cosf(am), emi = sinf(am);
                const float edr = cosf(ad), edi = sinf(ad);
                // U = [[e_m*ct, -e_d*st], [conj(e_d)*st, conj(e_m)*ct]]
                const float u00r =  emr * ct, u00i =  emi * ct;
                const float u01r = -edr * st, u01i = -edi * st;
                const float u10r =  edr * st, u10i = -edi * st;
                const float u11r =  emr * ct, u11i = -emi * ct;
                const int m = 1 << (3 - w);
#pragma unroll
                for (int i = 0; i < DIM; ++i) {
                    if (i & m) continue;
                    const int j = i | m;
                    const float ar = re[i], ai = im[i], br = re[j], bi = im[j];
                    re[i] = u00r * ar - u00i * ai + u01r * br - u01i * bi;
                    im[i] = u00r * ai + u00i * ar + u01r * bi + u01i * br;
                    re[j] = u10r * ar - u10i * ai + u11r * br - u11i * bi;
                    im[j] = u10r * ai + u10i * ar + u11r * bi + u11i * br;
                }
            }
            const int r = (l % (NQ - 1)) + 1;
            for (int w = 0; w < NQ; ++w) {
                const int t = (w + r) % NQ;
                const int cm = 1 << (3 - w);
                const int tm = 1 << (3 - t);
#pragma unroll
                for (int i = 0; i < DIM; ++i) {
                    if ((i & cm) && !(i & tm)) {
                        const int j = i | tm;
                        float tr = re[i]; re[i] = re[j]; re[j] = tr;
                        float ti = im[i]; im[i] = im[j]; im[j] = ti;
                    }
                }
            }
        }

        // PauliZ expvals
        float p[DIM];
#pragma unroll
        for (int i = 0; i < DIM; ++i) p[i] = re[i] * re[i] + im[i] * im[i];
        for (int w = 0; w < NQ; ++w) {
            const int m = 1 << (3 - w);
            float ev = 0.f;
#pragma unroll
            for (int i = 0; i < DIM; ++i) ev += (i & m) ? -p[i] : p[i];
            sref[b][w] = ev;
        }
    }
    __syncthreads();

    // gates1p[b,c] = 1 + sigmoid(refined @ proj_w^T + proj_b)
    const int c = tid;
    const float pw0 = proj_w[c * NQ + 0], pw1 = proj_w[c * NQ + 1];
    const float pw2 = proj_w[c * NQ + 2], pw3 = proj_w[c * NQ + 3];
    const float pb = proj_b[c];
    for (int b = 0; b < BATCH; ++b) {
        const float acc = sref[b][0] * pw0 + sref[b][1] * pw1 +
                          sref[b][2] * pw2 + sref[b][3] * pw3 + pb;
        gates1p[b * CH + c] = 1.f + 1.f / (1.f + expf(-acc));
    }
}

// ---------------- Kernel 3: out = x * gates1p[b,c] ----------------
// Non-temporal stores: out streams to HBM without evicting x from the 256 MiB
// Infinity Cache, so the x re-read (and next replay's pool read) stays L3-hit.
__global__ void scale_kernel(const float* __restrict__ x,
                             const float* __restrict__ gates1p,
                             float* __restrict__ out) {
    const floatx4* x4 = (const floatx4*)x;
    floatx4* o4 = (floatx4*)out;
    const int n4 = BATCH * CH * HW / 4;   // 16,777,216
    for (int idx = blockIdx.x * blockDim.x + threadIdx.x; idx < n4;
         idx += gridDim.x * blockDim.x) {
        const int bc = idx >> 12;         // (idx*4) / 16384
        const float g = gates1p[bc];
        floatx4 v = x4[idx];
        v *= g;
        __builtin_nontemporal_store(v, &o4[idx]);
    }
}

extern "C" void kernel_launch(void* const* d_in, const int* in_sizes, int n_in,
                              void* d_out, int out_size, void* d_ws, size_t ws_size,
                              hipStream_t stream) {
    const float* x      = (const float*)d_in[0];
    const float* enc_w  = (const float*)d_in[1];
    const float* enc_b  = (const float*)d_in[2];
    const float* qw     = (const float*)d_in[3];
    const float* proj_w = (const float*)d_in[4];
    const float* proj_b = (const float*)d_in[5];
    float* out = (float*)d_out;

    float* pooled  = (float*)d_ws;            // [16*256]
    float* gates1p = pooled + BATCH * CH;     // [16*256]

    pool_kernel<<<BATCH * CH, 256, 0, stream>>>(x, pooled);
    gate_kernel<<<1, 256, 0, stream>>>(pooled, enc_w, enc_b, qw, proj_w, proj_b, gates1p);
    scale_kernel<<<2048, 256, 0, stream>>>(x, gates1p, out);
}

// Round 4
// 149.895 us; speedup vs baseline: 1.2973x; 1.0281x over previous
//
#include <hip/hip_runtime.h>
#include <math.h>

#define NQ 4
#define NL 2
#define DIM 16          // 2^NQ
#define BATCH 16
#define CH 256
#define HW 16384        // 128*128

typedef float floatx4 __attribute__((ext_vector_type(4)));

// ---------------- Kernel 1: per-(b,c) mean over H*W ----------------
__global__ void pool_kernel(const float* __restrict__ x, float* __restrict__ pooled) {
    const int bc = blockIdx.x;                       // 0..4095
    const floatx4* x4 = (const floatx4*)(x + (size_t)bc * HW);
    const int tid = threadIdx.x;                     // 256 threads
    float s = 0.f;
#pragma unroll
    for (int k = 0; k < 16; ++k) {                   // 16 float4 / thread = 16384 elems/block
        floatx4 v = x4[tid + k * 256];
        s += v.x + v.y + v.z + v.w;
    }
    // wave (64-lane) shuffle reduce
#pragma unroll
    for (int off = 32; off > 0; off >>= 1) s += __shfl_down(s, off, 64);
    __shared__ float partial[4];
    if ((tid & 63) == 0) partial[tid >> 6] = s;
    __syncthreads();
    if (tid == 0)
        pooled[bc] = (partial[0] + partial[1] + partial[2] + partial[3]) * (1.0f / HW);
}

// ---------------- Kernel 2: encoder + 4-qubit circuit + gates ----------------
// one block, 256 threads. Writes gates1p[b*CH+c] = 1 + sigmoid(...)
__global__ void gate_kernel(const float* __restrict__ pooled,
                            const float* __restrict__ enc_w,  // [NQ, CH]
                            const float* __restrict__ enc_b,  // [NQ]
                            const float* __restrict__ qw,     // [NL, NQ, 3]
                            const float* __restrict__ proj_w, // [CH, NQ]
                            const float* __restrict__ proj_b, // [CH]
                            float* __restrict__ gates1p) {
    __shared__ float sp[BATCH * CH];
    __shared__ float sz[BATCH][NQ];
    __shared__ float sref[BATCH][NQ];
    const int tid = threadIdx.x;

    for (int i = tid; i < BATCH * CH; i += 256) sp[i] = pooled[i];
    __syncthreads();

    // z = tanh(pooled @ enc_w^T + enc_b) : 64 (b,q) dots over 256
    if (tid < BATCH * NQ) {
        const int b = tid >> 2, q = tid & 3;
        float acc = enc_b[q];
        for (int c = 0; c < CH; ++c) acc += sp[b * CH + c] * enc_w[q * CH + c];
        sz[b][q] = tanhf(acc);
    }
    __syncthreads();

    // statevector simulation: one thread per batch
    if (tid < BATCH) {
        const int b = tid;
        float re[DIM], im[DIM];
#pragma unroll
        for (int i = 0; i < DIM; ++i) { re[i] = 0.f; im[i] = 0.f; }
        re[0] = 1.f;

        // AngleEmbedding: RY(z_w) on wire w (wire 0 = MSB of state index)
        for (int w = 0; w < NQ; ++w) {
            const float a = sz[b][w] * 0.5f;
            const float cc = cosf(a), ss = sinf(a);
            const int m = 1 << (3 - w);
#pragma unroll
            for (int i = 0; i < DIM; ++i) {
                if (i & m) continue;
                const int j = i | m;
                const float r0 = cc * re[i] - ss * re[j];
                const float i0 = cc * im[i] - ss * im[j];
                const float r1 = ss * re[i] + cc * re[j];
                const float i1 = ss * im[i] + cc * im[j];
                re[i] = r0; im[i] = i0; re[j] = r1; im[j] = i1;
            }
        }

        // StronglyEntanglingLayers
        for (int l = 0; l < NL; ++l) {
            for (int w = 0; w < NQ; ++w) {
                const float phi = qw[(l * NQ + w) * 3 + 0];
                const float th  = qw[(l * NQ + w) * 3 + 1];
                const float om  = qw[(l * NQ + w) * 3 + 2];
                const float ct = cosf(0.5f * th), st = sinf(0.5f * th);
                const float am = -0.5f * (phi + om);   // e_m = exp(i*am)
                const float ad =  0.5f * (phi - om);   // e_d = exp(i*ad)
                const float emr = cosf(am), emi = sinf(am);
                const float edr = cosf(ad), edi = sinf(ad);
                // U = [[e_m*ct, -e_d*st], [conj(e_d)*st, conj(e_m)*ct]]
                const float u00r =  emr * ct, u00i =  emi * ct;
                const float u01r = -edr * st, u01i = -edi * st;
                const float u10r =  edr * st, u10i = -edi * st;
                const float u11r =  emr * ct, u11i = -emi * ct;
                const int m = 1 << (3 - w);
#pragma unroll
                for (int i = 0; i < DIM; ++i) {
                    if (i & m) continue;
                    const int j = i | m;
                    const float ar = re[i], ai = im[i], br = re[j], bi = im[j];
                    re[i] = u00r * ar - u00i * ai + u01r * br - u01i * bi;
                    im[i] = u00r * ai + u00i * ar + u01r * bi + u01i * br;
                    re[j] = u10r * ar - u10i * ai + u11r * br - u11i * bi;
                    im[j] = u10r * ai + u10i * ar + u11r * bi + u11i * br;
                }
            }
            const int r = (l % (NQ - 1)) + 1;
            for (int w = 0; w < NQ; ++w) {
                const int t = (w + r) % NQ;
                const int cm = 1 << (3 - w);
                const int tm = 1 << (3 - t);
#pragma unroll
                for (int i = 0; i < DIM; ++i) {
                    if ((i & cm) && !(i & tm)) {
                        const int j = i | tm;
                        float tr = re[i]; re[i] = re[j]; re[j] = tr;
                        float ti = im[i]; im[i] = im[j]; im[j] = ti;
                    }
                }
            }
        }

        // PauliZ expvals
        float p[DIM];
#pragma unroll
        for (int i = 0; i < DIM; ++i) p[i] = re[i] * re[i] + im[i] * im[i];
        for (int w = 0; w < NQ; ++w) {
            const int m = 1 << (3 - w);
            float ev = 0.f;
#pragma unroll
            for (int i = 0; i < DIM; ++i) ev += (i & m) ? -p[i] : p[i];
            sref[b][w] = ev;
        }
    }
    __syncthreads();

    // gates1p[b,c] = 1 + sigmoid(refined @ proj_w^T + proj_b)
    const int c = tid;
    const float pw0 = proj_w[c * NQ + 0], pw1 = proj_w[c * NQ + 1];
    const float pw2 = proj_w[c * NQ + 2], pw3 = proj_w[c * NQ + 3];
    const float pb = proj_b[c];
    for (int b = 0; b < BATCH; ++b) {
        const float acc = sref[b][0] * pw0 + sref[b][1] * pw1 +
                          sref[b][2] * pw2 + sref[b][3] * pw3 + pb;
        gates1p[b * CH + c] = 1.f + 1.f / (1.f + expf(-acc));
    }
}

// ---------------- Kernel 3: out = x * gates1p[b,c] ----------------
// Each block owns 2048 consecutive float4 (32 KB), which lies entirely within
// one (b,c) slice (4096 float4/slice, chunks 2048-aligned) -> g is block-uniform
// (scalar load). 8 independent loads up front (MLP=8), then 8 nt stores so out
// streams to HBM without evicting x from the 256 MiB Infinity Cache.
__global__ void scale_kernel(const float* __restrict__ x,
                             const float* __restrict__ gates1p,
                             float* __restrict__ out) {
    const floatx4* x4 = (const floatx4*)x;
    floatx4* o4 = (floatx4*)out;
    const int base = blockIdx.x * 2048 + threadIdx.x;   // float4 index
    const float g = gates1p[blockIdx.x >> 1];           // 2 blocks per (b,c)
    floatx4 v[8];
#pragma unroll
    for (int k = 0; k < 8; ++k) v[k] = x4[base + k * 256];
#pragma unroll
    for (int k = 0; k < 8; ++k) {
        v[k] *= g;
        __builtin_nontemporal_store(v[k], &o4[base + k * 256]);
    }
}

extern "C" void kernel_launch(void* const* d_in, const int* in_sizes, int n_in,
                              void* d_out, int out_size, void* d_ws, size_t ws_size,
                              hipStream_t stream) {
    const float* x      = (const float*)d_in[0];
    const float* enc_w  = (const float*)d_in[1];
    const float* enc_b  = (const float*)d_in[2];
    const float* qw     = (const float*)d_in[3];
    const float* proj_w = (const float*)d_in[4];
    const float* proj_b = (const float*)d_in[5];
    float* out = (float*)d_out;

    float* pooled  = (float*)d_ws;            // [16*256]
    float* gates1p = pooled + BATCH * CH;     // [16*256]

    pool_kernel<<<BATCH * CH, 256, 0, stream>>>(x, pooled);
    gate_kernel<<<1, 256, 0, stream>>>(pooled, enc_w, enc_b, qw, proj_w, proj_b, gates1p);
    scale_kernel<<<8192, 256, 0, stream>>>(x, gates1p, out);
}

// Round 5
// 149.592 us; speedup vs baseline: 1.2999x; 1.0020x over previous
//
#include <hip/hip_runtime.h>
#include <math.h>

#define NQ 4
#define NL 2
#define DIM 16          // 2^NQ
#define BATCH 16
#define CH 256
#define HW 16384        // 128*128

typedef float floatx4 __attribute__((ext_vector_type(4)));

// ---------------- Kernel 1: per-(b,c) mean over H*W ----------------
__global__ void pool_kernel(const float* __restrict__ x, float* __restrict__ pooled) {
    const int bc = blockIdx.x;                       // 0..4095
    const floatx4* x4 = (const floatx4*)(x + (size_t)bc * HW);
    const int tid = threadIdx.x;                     // 256 threads
    float s = 0.f;
#pragma unroll
    for (int k = 0; k < 16; ++k) {                   // 16 float4 / thread = 16384 elems/block
        floatx4 v = x4[tid + k * 256];
        s += v.x + v.y + v.z + v.w;
    }
    // wave (64-lane) shuffle reduce
#pragma unroll
    for (int off = 32; off > 0; off >>= 1) s += __shfl_down(s, off, 64);
    __shared__ float partial[4];
    if ((tid & 63) == 0) partial[tid >> 6] = s;
    __syncthreads();
    if (tid == 0)
        pooled[bc] = (partial[0] + partial[1] + partial[2] + partial[3]) * (1.0f / HW);
}

// ---------------- Kernel 2: encoder + 4-qubit circuit + gates ----------------
// one block, 256 threads. Writes gates1p[b*CH+c] = 1 + sigmoid(...)
__global__ void gate_kernel(const float* __restrict__ pooled,
                            const float* __restrict__ enc_w,  // [NQ, CH]
                            const float* __restrict__ enc_b,  // [NQ]
                            const float* __restrict__ qw,     // [NL, NQ, 3]
                            const float* __restrict__ proj_w, // [CH, NQ]
                            const float* __restrict__ proj_b, // [CH]
                            float* __restrict__ gates1p) {
    __shared__ float sp[BATCH * CH];
    __shared__ float sz[BATCH][NQ];
    __shared__ float sref[BATCH][NQ];
    const int tid = threadIdx.x;

    for (int i = tid; i < BATCH * CH; i += 256) sp[i] = pooled[i];
    __syncthreads();

    // z = tanh(pooled @ enc_w^T + enc_b) : 64 (b,q) dots over 256
    if (tid < BATCH * NQ) {
        const int b = tid >> 2, q = tid & 3;
        float acc = enc_b[q];
        for (int c = 0; c < CH; ++c) acc += sp[b * CH + c] * enc_w[q * CH + c];
        sz[b][q] = tanhf(acc);
    }
    __syncthreads();

    // statevector simulation: one thread per batch
    if (tid < BATCH) {
        const int b = tid;
        float re[DIM], im[DIM];
#pragma unroll
        for (int i = 0; i < DIM; ++i) { re[i] = 0.f; im[i] = 0.f; }
        re[0] = 1.f;

        // AngleEmbedding: RY(z_w) on wire w (wire 0 = MSB of state index)
        for (int w = 0; w < NQ; ++w) {
            const float a = sz[b][w] * 0.5f;
            const float cc = cosf(a), ss = sinf(a);
            const int m = 1 << (3 - w);
#pragma unroll
            for (int i = 0; i < DIM; ++i) {
                if (i & m) continue;
                const int j = i | m;
                const float r0 = cc * re[i] - ss * re[j];
                const float i0 = cc * im[i] - ss * im[j];
                const float r1 = ss * re[i] + cc * re[j];
                const float i1 = ss * im[i] + cc * im[j];
                re[i] = r0; im[i] = i0; re[j] = r1; im[j] = i1;
            }
        }

        // StronglyEntanglingLayers
        for (int l = 0; l < NL; ++l) {
            for (int w = 0; w < NQ; ++w) {
                const float phi = qw[(l * NQ + w) * 3 + 0];
                const float th  = qw[(l * NQ + w) * 3 + 1];
                const float om  = qw[(l * NQ + w) * 3 + 2];
                const float ct = cosf(0.5f * th), st = sinf(0.5f * th);
                const float am = -0.5f * (phi + om);   // e_m = exp(i*am)
                const float ad =  0.5f * (phi - om);   // e_d = exp(i*ad)
                const float emr = cosf(am), emi = sinf(am);
                const float edr = cosf(ad), edi = sinf(ad);
                // U = [[e_m*ct, -e_d*st], [conj(e_d)*st, conj(e_m)*ct]]
                const float u00r =  emr * ct, u00i =  emi * ct;
                const float u01r = -edr * st, u01i = -edi * st;
                const float u10r =  edr * st, u10i = -edi * st;
                const float u11r =  emr * ct, u11i = -emi * ct;
                const int m = 1 << (3 - w);
#pragma unroll
                for (int i = 0; i < DIM; ++i) {
                    if (i & m) continue;
                    const int j = i | m;
                    const float ar = re[i], ai = im[i], br = re[j], bi = im[j];
                    re[i] = u00r * ar - u00i * ai + u01r * br - u01i * bi;
                    im[i] = u00r * ai + u00i * ar + u01r * bi + u01i * br;
                    re[j] = u10r * ar - u10i * ai + u11r * br - u11i * bi;
                    im[j] = u10r * ai + u10i * ar + u11r * bi + u11i * br;
                }
            }
            const int r = (l % (NQ - 1)) + 1;
            for (int w = 0; w < NQ; ++w) {
                const int t = (w + r) % NQ;
                const int cm = 1 << (3 - w);
                const int tm = 1 << (3 - t);
#pragma unroll
                for (int i = 0; i < DIM; ++i) {
                    if ((i & cm) && !(i & tm)) {
                        const int j = i | tm;
                        float tr = re[i]; re[i] = re[j]; re[j] = tr;
                        float ti = im[i]; im[i] = im[j]; im[j] = ti;
                    }
                }
            }
        }

        // PauliZ expvals
        float p[DIM];
#pragma unroll
        for (int i = 0; i < DIM; ++i) p[i] = re[i] * re[i] + im[i] * im[i];
        for (int w = 0; w < NQ; ++w) {
            const int m = 1 << (3 - w);
            float ev = 0.f;
#pragma unroll
            for (int i = 0; i < DIM; ++i) ev += (i & m) ? -p[i] : p[i];
            sref[b][w] = ev;
        }
    }
    __syncthreads();

    // gates1p[b,c] = 1 + sigmoid(refined @ proj_w^T + proj_b)
    const int c = tid;
    const float pw0 = proj_w[c * NQ + 0], pw1 = proj_w[c * NQ + 1];
    const float pw2 = proj_w[c * NQ + 2], pw3 = proj_w[c * NQ + 3];
    const float pb = proj_b[c];
    for (int b = 0; b < BATCH; ++b) {
        const float acc = sref[b][0] * pw0 + sref[b][1] * pw1 +
                          sref[b][2] * pw2 + sref[b][3] * pw3 + pb;
        gates1p[b * CH + c] = 1.f + 1.f / (1.f + expf(-acc));
    }
}

// ---------------- Kernel 3: out = x * gates1p[b,c] ----------------
// REVERSE traversal: pool touched x in forward order; with x == L3 capacity,
// forward re-read would LRU-thrash (victim is always the next-needed line).
// Reading newest-first makes scale's x reads (and next replay's pool reads,
// which again run opposite to scale's order) mostly L3 hits. nt stores keep
// `out` from evicting x.
__global__ void scale_kernel(const float* __restrict__ x,
                             const float* __restrict__ gates1p,
                             float* __restrict__ out) {
    const floatx4* x4 = (const floatx4*)x;
    floatx4* o4 = (floatx4*)out;
    const int chunk = 8191 - blockIdx.x;                // reverse order
    const int base = chunk * 2048 + threadIdx.x;        // float4 index
    const float g = gates1p[chunk >> 1];                // 2 chunks per (b,c)
    floatx4 v[8];
#pragma unroll
    for (int k = 0; k < 8; ++k) v[k] = x4[base + k * 256];
#pragma unroll
    for (int k = 0; k < 8; ++k) {
        v[k] *= g;
        __builtin_nontemporal_store(v[k], &o4[base + k * 256]);
    }
}

extern "C" void kernel_launch(void* const* d_in, const int* in_sizes, int n_in,
                              void* d_out, int out_size, void* d_ws, size_t ws_size,
                              hipStream_t stream) {
    const float* x      = (const float*)d_in[0];
    const float* enc_w  = (const float*)d_in[1];
    const float* enc_b  = (const float*)d_in[2];
    const float* qw     = (const float*)d_in[3];
    const float* proj_w = (const float*)d_in[4];
    const float* proj_b = (const float*)d_in[5];
    float* out = (float*)d_out;

    float* pooled  = (float*)d_ws;            // [16*256]
    float* gates1p = pooled + BATCH * CH;     // [16*256]

    pool_kernel<<<BATCH * CH, 256, 0, stream>>>(x, pooled);
    gate_kernel<<<1, 256, 0, stream>>>(pooled, enc_w, enc_b, qw, proj_w, proj_b, gates1p);
    scale_kernel<<<8192, 256, 0, stream>>>(x, gates1p, out);
}